// Round 12
// baseline (222.063 us; speedup 1.0000x reference)
//
#include <hip/hip_runtime.h>

// B=16, C=80, layer sizes 128/64/32.
// d_in order: heat0, tl0, br0, heat1, tl1, br1, heat2, tl2, br2.
//
// Static-threshold design: collect all heat elements >= T(l), sort the
// 4096-padded candidate list exactly by (score desc, idx asc), take first K.
// R12: collect rewritten for MLP — 8 independent float4 loads in flight per
// thread, direct global candidate write (no LDS staging; R11 was memory-
// latency-bound at 1.1 TB/s, occ 27%). Sort stays split: sortA (384 blocks,
// per-wave 512-elem register bitonic) + sortB (48x4, merge-rank scatter).
// Cold exact-repair fallback in sortB covers pathological inputs.

#define NB 1024      // repair-path histogram buckets
#define CHUNK 32768  // elements per collect block

__device__ __forceinline__ unsigned int ord_f32(float f) {
    unsigned int b = __float_as_uint(f);
    return (b & 0x80000000u) ? ~b : (b | 0x80000000u);
}
__device__ __forceinline__ float unord_f32(unsigned int o) {
    unsigned int b = (o & 0x80000000u) ? (o & 0x7fffffffu) : ~o;
    return __uint_as_float(b);
}
__device__ __forceinline__ int bucket_of(float f) {
    int bi = (int)(f * (float)NB);
    bi = bi < 0 ? 0 : (bi > NB - 1 ? NB - 1 : bi);
    return bi;
}

__device__ __forceinline__ int layer_N(int l)   { return (l == 0) ? 1310720 : (l == 1) ? 327680 : 81920; }
__device__ __forceinline__ int nchunks(int l)   { return (l == 0) ? 40 : (l == 1) ? 10 : 3; }
__device__ __forceinline__ int chunk_base(int l){ return (l == 0) ? 0 : (l == 1) ? 640 : 800; }
__device__ __forceinline__ float TL_of(int l)   { return (l == 0) ? 0.998046875f : (l == 1) ? 0.9921875f : 0.98125f; }
// expected counts per (b,l): 2560 / 2560 / 1536; bounds [K, 4096] at >11 sigma
__device__ __forceinline__ int seg_cap(int l)   { return (l == 0) ? 256 : (l == 1) ? 768 : 1024; }
__device__ __forceinline__ int loose_base(int l){ return (l == 0) ? 0 : (l == 1) ? 163840 : 286720; } // entries
// loose total: 40*16*256 + 10*16*768 + 3*16*1024 = 335872 entries

// ---------------- collect: one heat pass, 8-deep MLP, direct global write ----------------
__global__ __launch_bounds__(256) void collect_kernel(
    const float* __restrict__ h0, const float* __restrict__ h1, const float* __restrict__ h2,
    int* __restrict__ pbc, unsigned long long* __restrict__ loose)
{
    int l = blockIdx.z, b = blockIdx.y, chunk = blockIdx.x;
    int nc = nchunks(l);
    if (chunk >= nc) return;
    int N = layer_N(l);
    const float* heat = (l == 0) ? h0 : (l == 1) ? h1 : h2;
    float TL = TL_of(l);
    int cap = seg_cap(l);
    unsigned long long* seg = loose + loose_base(l) + (size_t)(b * nc + chunk) * cap;

    __shared__ int lc;
    if (threadIdx.x == 0) lc = 0;
    __syncthreads();

    const float4* p = (const float4*)(heat + (size_t)b * N + (size_t)chunk * CHUNK);
    int base = chunk * CHUNK;
    int n4 = (min(CHUNK, N - chunk * CHUNK)) >> 2;   // 8192 or 4096: multiple of 2048

    for (int i0 = threadIdx.x; i0 < n4; i0 += 256 * 8) {
        float4 va[8];
#pragma unroll
        for (int u = 0; u < 8; u++) va[u] = p[i0 + u * 256];   // 8 loads in flight
#pragma unroll
        for (int u = 0; u < 8; u++) {
            int i = i0 + u * 256;
            float vs[4] = {va[u].x, va[u].y, va[u].z, va[u].w};
#pragma unroll
            for (int cc = 0; cc < 4; cc++) {
                if (vs[cc] >= TL) {
                    int pos = atomicAdd(&lc, 1);
                    if (pos < cap) {
                        unsigned int idx = (unsigned int)(base + 4 * i + cc);
                        seg[pos] = ((unsigned long long)ord_f32(vs[cc]) << 32) | (unsigned int)(~idx);
                    }
                }
            }
        }
    }
    __syncthreads();
    if (threadIdx.x == 0) pbc[chunk_base(l) + b * nc + chunk] = lc;   // raw count
}

// ---------------- per-wave 512-elem in-register bitonic (descending), static indices ----------------
__device__ __forceinline__ unsigned long long shfl_xor_u64(unsigned long long a, int j) {
    unsigned int lo = (unsigned int)a, hi = (unsigned int)(a >> 32);
    lo = (unsigned int)__shfl_xor((int)lo, j, 64);
    hi = (unsigned int)__shfl_xor((int)hi, j, 64);
    return ((unsigned long long)hi << 32) | lo;
}

template<int K, int J>
struct PhaseH {
    static __device__ __forceinline__ void run(unsigned long long (&v)[8], int lane) {
        constexpr int JR = J >> 6;   // J in 64..256 -> JR in {1,2,4}
#pragma unroll
        for (int r = 0; r < 8; r++) {
            if ((r & JR) == 0) {
                int i = (r << 6) | lane;   // local index in [0,512)
                unsigned long long a = v[r], bb = v[r | JR];
                bool sw = ((i & K) == 0) ? (a < bb) : (a > bb);
                if (sw) { v[r] = bb; v[r | JR] = a; }
            }
        }
        PhaseH<K, (J >> 1)>::run(v, lane);
    }
};

template<int K>
struct PhaseH<K, 32> {
    static __device__ __forceinline__ void run(unsigned long long (&v)[8], int lane) {
#pragma unroll
        for (int js = 32; js >= 1; js >>= 1) {
            if (K > js) {
#pragma unroll
                for (int r = 0; r < 8; r++) {
                    unsigned long long a = v[r];
                    unsigned long long w = shfl_xor_u64(a, js);
                    int i = (r << 6) | lane;
                    bool upper = (lane & js) != 0;
                    bool keep_max = (((i & K) == 0) != upper);
                    bool agw = a > w;
                    v[r] = (keep_max == agw) ? a : w;
                }
            }
        }
    }
};

template<int K>
struct StageH {
    static __device__ __forceinline__ void run(unsigned long long (&v)[8], int lane) {
        PhaseH<K, (K > 64 ? (K >> 1) : 32)>::run(v, lane);
        StageH<(K << 1)>::run(v, lane);
    }
};
template<>
struct StageH<1024> {
    static __device__ __forceinline__ void run(unsigned long long (&)[8], int) {}
};

// ---------------- sortA: one wave per (bl, w): sort sublist w (512 elems) ----------------
__global__ __launch_bounds__(64) void sortA_kernel(
    const int* __restrict__ pbc, const unsigned long long* __restrict__ loose,
    unsigned long long* __restrict__ subl, int* __restrict__ badf)
{
    int bx = blockIdx.x;           // 0..383
    int bl = bx >> 3, w = bx & 7;
    int l = bl >> 4, b = bl & 15;
    int K = (l == 2) ? 1024 : 2000;
    int nc = nchunks(l);
    int cap = seg_cap(l);
    int lane = threadIdx.x;

    __shared__ int offs[64];

    // wave-parallel prefix of segment counts
    int raw = 0;
    if (lane < nc) raw = pbc[chunk_base(l) + b * nc + lane];
    int cnt_c = min(raw, cap);
    bool ovf = (lane < nc) && (raw > cap);
    unsigned long long ovfmask = __ballot(ovf);
    int x = cnt_c;
#pragma unroll
    for (int off = 1; off < 64; off <<= 1) {
        int y = __shfl_up(x, off, 64);
        if (lane >= off) x += y;
    }
    int tot = __shfl(x, 63, 64);

    offs[lane] = 0x7fffffff;
    __syncthreads();
    if (lane < nc) offs[lane + 1] = x;
    if (lane == 0) offs[0] = 0;
    __syncthreads();

    bool bad = (ovfmask != 0ull) || (tot < K) || (tot > 4096);
    if (lane == 0) badf[bl] = bad ? 1 : 0;   // 8 blocks write same value: benign
    if (bad) return;

    // gather window [w*512, w*512+512) from segments (6-step static search on offs)
    const unsigned long long* lb = loose + loose_base(l) + (size_t)b * nc * cap;
    unsigned long long v[8];
#pragma unroll
    for (int r = 0; r < 8; r++) {
        int g = (w << 9) | (r << 6) | lane;
        unsigned long long key;
        if (g >= tot) {
            key = (unsigned long long)g;   // unique pad, < any real key
        } else {
            int c = 0, oc = 0;
#pragma unroll
            for (int step = 32; step >= 1; step >>= 1) {
                int cc = c + step;
                int ov = offs[cc];         // cc <= 63
                if (ov <= g) { c = cc; oc = ov; }
            }
            key = lb[(size_t)c * cap + (g - oc)];
        }
        v[r] = key;
    }

    StageH<2>::run(v, lane);   // descending 512-elem sort, barrier-free

    unsigned long long* dst = subl + (size_t)bl * 4096 + (w << 9);
#pragma unroll
    for (int r = 0; r < 8; r++) dst[(r << 6) | lane] = v[r];
}

// ---------------- generic LDS bitonic (descending), loop-based (fallback only) ----------------
__device__ void bitonic_desc(unsigned long long* d, int n, int tid, int nt) {
    for (int k = 2; k <= n; k <<= 1) {
        for (int j = k >> 1; j > 0; j >>= 1) {
            __syncthreads();
            for (int i = tid; i < n; i += nt) {
                int ixj = i ^ j;
                if (ixj > i) {
                    unsigned long long a = d[i], bb = d[ixj];
                    bool sw = ((i & k) == 0) ? (a < bb) : (a > bb);
                    if (sw) { d[i] = bb; d[ixj] = a; }
                }
            }
        }
    }
    __syncthreads();
}

// ---------------- sortB: merge-rank 8 sorted sublists -> global sorted cand ----------------
__global__ __launch_bounds__(512) void sortB_kernel(
    const float* __restrict__ h0, const float* __restrict__ h1, const float* __restrict__ h2,
    const int* __restrict__ pbc, const unsigned long long* __restrict__ loose,
    const int* __restrict__ badf, const unsigned long long* __restrict__ subl,
    unsigned long long* __restrict__ cand)
{
    int bl = blockIdx.x;
    int part = blockIdx.y;         // 0..3, each ranks 1024 elements
    int l = bl >> 4, b = bl & 15;
    int K = (l == 2) ? 1024 : 2000;
    int tid = threadIdx.x;

    __shared__ unsigned long long A[4096];
    unsigned long long* cd = cand + (size_t)bl * 4096;

    if (!badf[bl]) {
        const unsigned long long* sl = subl + (size_t)bl * 4096;
        for (int i = tid; i < 4096; i += 512) A[i] = sl[i];
        __syncthreads();

#pragma unroll
        for (int e0 = 0; e0 < 2; e0++) {
            int wsrc = (part << 1) | e0;      // source sublist (uniform)
            unsigned long long key = A[(wsrc << 9) | tid];
            int rank = tid;                    // position within own sorted sublist
#pragma unroll
            for (int q = 0; q < 7; q++) {
                int w2 = q + (q >= wsrc ? 1 : 0);
                int lo = 0;
                for (int h = 256; h >= 1; h >>= 1) {          // rolled: small code, 7-way MLP
                    unsigned long long p = A[(w2 << 9) + lo + h - 1];
                    lo += (p > key) ? h : 0;
                }
                unsigned long long p = A[(w2 << 9) + lo];     // lo <= 511
                rank += lo + ((p > key) ? 1 : 0);
            }
            cd[rank] = key;   // keys globally unique -> rank is a permutation
        }
    } else {
        // ---- cold exact repair: full rescan + monolithic block bitonic (never for sane inputs)
        if (part != 0) return;
        __shared__ int lh[NB];
        __shared__ int st, lc2;
        for (int i = tid; i < NB; i += 512) lh[i] = 0;
        if (tid == 0) lc2 = 0;
        __syncthreads();
        int N = layer_N(l);
        const float* hp = ((l == 0) ? h0 : (l == 1) ? h1 : h2) + (size_t)b * N;
        for (int i = tid; i < N; i += 512) atomicAdd(&lh[bucket_of(hp[i])], 1);
        __syncthreads();
        if (tid == 0) {
            int acc = 0, bidx;
            for (bidx = NB - 1; bidx > 0; bidx--) {
                acc += lh[bidx];
                if (acc >= K) break;
            }
            st = bidx;
        }
        __syncthreads();
        int t = st;
        for (int i = tid; i < N; i += 512) {
            float xx = hp[i];
            if (bucket_of(xx) >= t) {
                int pos = atomicAdd(&lc2, 1);
                if (pos < 4096)
                    A[pos] = ((unsigned long long)ord_f32(xx) << 32) | (unsigned int)(~(unsigned int)i);
            }
        }
        __syncthreads();
        for (int i = min(lc2, 4096) + tid; i < 4096; i += 512) A[i] = (unsigned long long)i;
        bitonic_desc(A, 4096, tid, 512);
        for (int i = tid; i < 4096; i += 512) cd[i] = A[i];
    }
}

// ---------------- build det: validity, stable partition, write rows ----------------
__global__ __launch_bounds__(1024) void build_kernel(
    const float* __restrict__ t0, const float* __restrict__ t1, const float* __restrict__ t2,
    const float* __restrict__ r0, const float* __restrict__ r1, const float* __restrict__ r2,
    const unsigned long long* __restrict__ cand, float* __restrict__ det)
{
    int l = blockIdx.x >> 4;
    int b = blockIdx.x & 15;
    int bl = l * 16 + b;
    int HW = (l == 0) ? 16384 : (l == 1) ? 4096 : 1024;
    int W  = (l == 0) ? 128 : (l == 1) ? 64 : 32;
    int K  = (l == 2) ? 1024 : 2000;
    float scale = (l == 0) ? 8.f : (l == 1) ? 16.f : 32.f;
    const float* tlp = (l == 0) ? t0 : (l == 1) ? t1 : t2;
    const float* brp = (l == 0) ? r0 : (l == 1) ? r1 : r2;

    const unsigned long long* srt = cand + (size_t)bl * 4096;

    __shared__ int wsum[16];
    int tid = threadIdx.x;
    int lane = tid & 63, wid = tid >> 6;

    // each thread handles k = 2*tid, 2*tid+1 (consecutive -> correct scan order)
    float s_[2], bx_[2][4];
    int f_[2];
#pragma unroll
    for (int q = 0; q < 2; q++) {
        int k = 2 * tid + q;
        f_[q] = 0;
        if (k < K) {
            unsigned long long kk = srt[k];
            unsigned int idx = ~(unsigned int)kk;
            float score = unord_f32((unsigned int)(kk >> 32));
            int sp = (int)(idx % (unsigned)HW);
            float xs = (float)(sp % W), ys = (float)(sp / W);
            float tv0 = tlp[((size_t)b * 2 + 0) * HW + sp];
            float tv1 = tlp[((size_t)b * 2 + 1) * HW + sp];
            float bv0 = brp[((size_t)b * 2 + 0) * HW + sp];
            float bv1 = brp[((size_t)b * 2 + 1) * HW + sp];
            float tlx = __fsub_rn(xs, __fadd_rn(__fmul_rn(1.5f, tv0), 2.25f));
            float tly = __fsub_rn(ys, __fadd_rn(__fmul_rn(1.5f, tv1), 2.25f));
            float brx = __fadd_rn(xs, __fadd_rn(__fmul_rn(1.5f, bv0), 2.25f));
            float bry = __fadd_rn(ys, __fadd_rn(__fmul_rn(1.5f, bv1), 2.25f));
            bool invalid = (brx < tlx) || (bry < tly);
            f_[q] = invalid ? 0 : 1;
            s_[q] = invalid ? -1.0f : score;
            bx_[q][0] = __fmul_rn(tlx, scale);
            bx_[q][1] = __fmul_rn(tly, scale);
            bx_[q][2] = __fmul_rn(brx, scale);
            bx_[q][3] = __fmul_rn(bry, scale);
        }
    }
    int mysum = f_[0] + f_[1];

    // wave-level inclusive scan
    int x = mysum;
#pragma unroll
    for (int off = 1; off < 64; off <<= 1) {
        int y = __shfl_up(x, off, 64);
        if (lane >= off) x += y;
    }
    if (lane == 63) wsum[wid] = x;
    __syncthreads();
    if (wid == 0 && lane < 16) {
        int s = wsum[lane];
#pragma unroll
        for (int off = 1; off < 16; off <<= 1) {
            int y = __shfl_up(s, off, 64);
            if (lane >= off) s += y;
        }
        wsum[lane] = s;
    }
    __syncthreads();
    int wave_off = (wid > 0) ? wsum[wid - 1] : 0;
    int V = wsum[15];
    int base_excl = (x + wave_off) - mysum;

    float* dbase = det + ((size_t)b * 3000 + (size_t)l * 1000) * 7;
#pragma unroll
    for (int q = 0; q < 2; q++) {
        int k = 2 * tid + q;
        if (k < K) {
            int pos = base_excl + (q == 1 ? f_[0] : 0);
            int rank = f_[q] ? pos : V + (k - pos);
            if (rank < 1000 && rank != 6) {
                float* drow = dbase + (size_t)rank * 7;
                drow[0] = s_[q];
                drow[1] = bx_[q][0];
                drow[2] = bx_[q][1];
                drow[3] = bx_[q][2];
                drow[4] = bx_[q][3];
                drow[5] = 0.f;
                drow[6] = 0.f;
            }
        }
    }
    if (tid == 0) {
        float lv = (float)l;
        float* drow = dbase + 6 * 7;
#pragma unroll
        for (int j = 0; j < 7; j++) drow[j] = lv;
    }
}

// ---------------- final: merge-rank of 3 sorted lists (+3 clobbered singletons) ----------------
__device__ __forceinline__ bool key_gt(float sa, int ga, float sb, int gb) {
    return (sa > sb) || (sa == sb && ga < gb);
}

__global__ __launch_bounds__(1024) void final_kernel(const float* __restrict__ det,
                                                     float* __restrict__ out)
{
    int b = blockIdx.x;
    __shared__ float sc[3000];
    int tid = threadIdx.x;
    const float* dbase = det + (size_t)b * 3000 * 7;
    for (int i = tid; i < 3000; i += 1024) sc[i] = dbase[(size_t)i * 7];
    __syncthreads();

    for (int e = tid; e < 3000; e += 1024) {
        float se = sc[e];
        int ge = e;
        int rank = 0;
#pragma unroll
        for (int lp = 0; lp < 3; lp++) {
            int lo = 0, hiB = 999;
            while (lo < hiB) {
                int mid = (lo + hiB) >> 1;
                int p = mid + (mid >= 6 ? 1 : 0);
                int g = lp * 1000 + p;
                if (key_gt(sc[g], g, se, ge)) lo = mid + 1; else hiB = mid;
            }
            rank += lo;
        }
#pragma unroll
        for (int ls = 0; ls < 3; ls++) {
            int g = ls * 1000 + 6;
            if (g != e && key_gt((float)ls, g, se, ge)) rank++;
        }
        if (rank < 1000) {
            const float* src = dbase + (size_t)e * 7;
            float* dst = out + ((size_t)b * 1000 + rank) * 7;
#pragma unroll
            for (int j = 0; j < 7; j++) dst[j] = src[j];
        }
    }
}

extern "C" void kernel_launch(void* const* d_in, const int* in_sizes, int n_in,
                              void* d_out, int out_size, void* d_ws, size_t ws_size,
                              hipStream_t stream)
{
    (void)in_sizes; (void)n_in; (void)out_size; (void)ws_size;
    const float* h0 = (const float*)d_in[0];
    const float* t0 = (const float*)d_in[1];
    const float* r0 = (const float*)d_in[2];
    const float* h1 = (const float*)d_in[3];
    const float* t1 = (const float*)d_in[4];
    const float* r1 = (const float*)d_in[5];
    const float* h2 = (const float*)d_in[6];
    const float* t2 = (const float*)d_in[7];
    const float* r2 = (const float*)d_in[8];
    float* out = (float*)d_out;

    // Workspace layout (bytes):
    //   pbc  : 848*4       = 3392      @ 0
    //   badf : 48*4        = 192       @ 3392     (always written by sortA)
    //   loose: 335872*8    = 2686976   @ 3584     (8B aligned)
    //   subl : 48*4096*8   = 1572864   @ 2690560  (8B aligned)
    //   cand : 48*4096*8   = 1572864   @ 4263424
    //   det  : 16*3000*7*4 = 1344000   @ 5836288
    char* ws = (char*)d_ws;
    int* pbc  = (int*)ws;
    int* badf = (int*)(ws + 3392);
    unsigned long long* loose = (unsigned long long*)(ws + 3584);
    unsigned long long* subl  = (unsigned long long*)(ws + 2690560);
    unsigned long long* cand  = (unsigned long long*)(ws + 4263424);
    float* det = (float*)(ws + 5836288);

    collect_kernel<<<dim3(40, 16, 3), 256, 0, stream>>>(h0, h1, h2, pbc, loose);
    sortA_kernel<<<384, 64, 0, stream>>>(pbc, loose, subl, badf);
    sortB_kernel<<<dim3(48, 4), 512, 0, stream>>>(h0, h1, h2, pbc, loose, badf, subl, cand);
    build_kernel<<<48, 1024, 0, stream>>>(t0, t1, t2, r0, r1, r2, cand, det);
    final_kernel<<<16, 1024, 0, stream>>>(det, out);
}

// Round 13
// 215.151 us; speedup vs baseline: 1.0321x; 1.0321x over previous
//
#include <hip/hip_runtime.h>

// B=16, C=80, layer sizes 128/64/32.
// d_in order: heat0, tl0, br0, heat1, tl1, br1, heat2, tl2, br2.
//
// Static-threshold design: collect all heat elements >= T(l), sort the
// 4096-padded candidate list exactly by (score desc, idx asc), take first K.
// R13: collect uses 1024-thread blocks (16 waves) -> ~53 waves/CU available,
// occupancy-saturated TLP hides memory latency (R12's source-level 8-deep ILP
// was defeated by the register allocator: VGPR=24 < 32 needed). Sort stays
// split: sortA (384 blocks, per-wave 512-elem register bitonic) + sortB
// (48x4, merge-rank scatter). Cold exact-repair fallback in sortB.

#define NB 1024      // repair-path histogram buckets
#define CHUNK 32768  // elements per collect block

__device__ __forceinline__ unsigned int ord_f32(float f) {
    unsigned int b = __float_as_uint(f);
    return (b & 0x80000000u) ? ~b : (b | 0x80000000u);
}
__device__ __forceinline__ float unord_f32(unsigned int o) {
    unsigned int b = (o & 0x80000000u) ? (o & 0x7fffffffu) : ~o;
    return __uint_as_float(b);
}
__device__ __forceinline__ int bucket_of(float f) {
    int bi = (int)(f * (float)NB);
    bi = bi < 0 ? 0 : (bi > NB - 1 ? NB - 1 : bi);
    return bi;
}

__device__ __forceinline__ int layer_N(int l)   { return (l == 0) ? 1310720 : (l == 1) ? 327680 : 81920; }
__device__ __forceinline__ int nchunks(int l)   { return (l == 0) ? 40 : (l == 1) ? 10 : 3; }
__device__ __forceinline__ int chunk_base(int l){ return (l == 0) ? 0 : (l == 1) ? 640 : 800; }
__device__ __forceinline__ float TL_of(int l)   { return (l == 0) ? 0.998046875f : (l == 1) ? 0.9921875f : 0.98125f; }
// expected counts per (b,l): 2560 / 2560 / 1536; bounds [K, 4096] at >11 sigma
__device__ __forceinline__ int seg_cap(int l)   { return (l == 0) ? 256 : (l == 1) ? 768 : 1024; }
__device__ __forceinline__ int loose_base(int l){ return (l == 0) ? 0 : (l == 1) ? 163840 : 286720; } // entries
// loose total: 40*16*256 + 10*16*768 + 3*16*1024 = 335872 entries

// ---------------- collect: one heat pass, 16 waves/block for TLP, direct global write ----------------
__global__ __launch_bounds__(1024) void collect_kernel(
    const float* __restrict__ h0, const float* __restrict__ h1, const float* __restrict__ h2,
    int* __restrict__ pbc, unsigned long long* __restrict__ loose)
{
    int l = blockIdx.z, b = blockIdx.y, chunk = blockIdx.x;
    int nc = nchunks(l);
    if (chunk >= nc) return;
    int N = layer_N(l);
    const float* heat = (l == 0) ? h0 : (l == 1) ? h1 : h2;
    float TL = TL_of(l);
    int cap = seg_cap(l);
    unsigned long long* seg = loose + loose_base(l) + (size_t)(b * nc + chunk) * cap;

    __shared__ int lc;
    if (threadIdx.x == 0) lc = 0;
    __syncthreads();

    const float4* p = (const float4*)(heat + (size_t)b * N + (size_t)chunk * CHUNK);
    int base = chunk * CHUNK;
    int n4 = (min(CHUNK, N - chunk * CHUNK)) >> 2;   // 8192 (full) or 4096 (l2 tail)
    int tid = threadIdx.x;

    if (n4 == 8192) {
        float4 va[8];
#pragma unroll
        for (int u = 0; u < 8; u++) va[u] = p[tid + u * 1024];
#pragma unroll
        for (int u = 0; u < 8; u++) {
            int i = tid + u * 1024;
            float vs[4] = {va[u].x, va[u].y, va[u].z, va[u].w};
#pragma unroll
            for (int cc = 0; cc < 4; cc++) {
                if (vs[cc] >= TL) {
                    int pos = atomicAdd(&lc, 1);
                    if (pos < cap) {
                        unsigned int idx = (unsigned int)(base + 4 * i + cc);
                        seg[pos] = ((unsigned long long)ord_f32(vs[cc]) << 32) | (unsigned int)(~idx);
                    }
                }
            }
        }
    } else {
        float4 va[4];
#pragma unroll
        for (int u = 0; u < 4; u++) va[u] = p[tid + u * 1024];
#pragma unroll
        for (int u = 0; u < 4; u++) {
            int i = tid + u * 1024;
            float vs[4] = {va[u].x, va[u].y, va[u].z, va[u].w};
#pragma unroll
            for (int cc = 0; cc < 4; cc++) {
                if (vs[cc] >= TL) {
                    int pos = atomicAdd(&lc, 1);
                    if (pos < cap) {
                        unsigned int idx = (unsigned int)(base + 4 * i + cc);
                        seg[pos] = ((unsigned long long)ord_f32(vs[cc]) << 32) | (unsigned int)(~idx);
                    }
                }
            }
        }
    }
    __syncthreads();
    if (threadIdx.x == 0) pbc[chunk_base(l) + b * nc + chunk] = lc;   // raw count
}

// ---------------- per-wave 512-elem in-register bitonic (descending), static indices ----------------
__device__ __forceinline__ unsigned long long shfl_xor_u64(unsigned long long a, int j) {
    unsigned int lo = (unsigned int)a, hi = (unsigned int)(a >> 32);
    lo = (unsigned int)__shfl_xor((int)lo, j, 64);
    hi = (unsigned int)__shfl_xor((int)hi, j, 64);
    return ((unsigned long long)hi << 32) | lo;
}

template<int K, int J>
struct PhaseH {
    static __device__ __forceinline__ void run(unsigned long long (&v)[8], int lane) {
        constexpr int JR = J >> 6;   // J in 64..256 -> JR in {1,2,4}
#pragma unroll
        for (int r = 0; r < 8; r++) {
            if ((r & JR) == 0) {
                int i = (r << 6) | lane;   // local index in [0,512)
                unsigned long long a = v[r], bb = v[r | JR];
                bool sw = ((i & K) == 0) ? (a < bb) : (a > bb);
                if (sw) { v[r] = bb; v[r | JR] = a; }
            }
        }
        PhaseH<K, (J >> 1)>::run(v, lane);
    }
};

template<int K>
struct PhaseH<K, 32> {
    static __device__ __forceinline__ void run(unsigned long long (&v)[8], int lane) {
#pragma unroll
        for (int js = 32; js >= 1; js >>= 1) {
            if (K > js) {
#pragma unroll
                for (int r = 0; r < 8; r++) {
                    unsigned long long a = v[r];
                    unsigned long long w = shfl_xor_u64(a, js);
                    int i = (r << 6) | lane;
                    bool upper = (lane & js) != 0;
                    bool keep_max = (((i & K) == 0) != upper);
                    bool agw = a > w;
                    v[r] = (keep_max == agw) ? a : w;
                }
            }
        }
    }
};

template<int K>
struct StageH {
    static __device__ __forceinline__ void run(unsigned long long (&v)[8], int lane) {
        PhaseH<K, (K > 64 ? (K >> 1) : 32)>::run(v, lane);
        StageH<(K << 1)>::run(v, lane);
    }
};
template<>
struct StageH<1024> {
    static __device__ __forceinline__ void run(unsigned long long (&)[8], int) {}
};

// ---------------- sortA: one wave per (bl, w): sort sublist w (512 elems) ----------------
__global__ __launch_bounds__(64) void sortA_kernel(
    const int* __restrict__ pbc, const unsigned long long* __restrict__ loose,
    unsigned long long* __restrict__ subl, int* __restrict__ badf)
{
    int bx = blockIdx.x;           // 0..383
    int bl = bx >> 3, w = bx & 7;
    int l = bl >> 4, b = bl & 15;
    int K = (l == 2) ? 1024 : 2000;
    int nc = nchunks(l);
    int cap = seg_cap(l);
    int lane = threadIdx.x;

    __shared__ int offs[64];

    // wave-parallel prefix of segment counts
    int raw = 0;
    if (lane < nc) raw = pbc[chunk_base(l) + b * nc + lane];
    int cnt_c = min(raw, cap);
    bool ovf = (lane < nc) && (raw > cap);
    unsigned long long ovfmask = __ballot(ovf);
    int x = cnt_c;
#pragma unroll
    for (int off = 1; off < 64; off <<= 1) {
        int y = __shfl_up(x, off, 64);
        if (lane >= off) x += y;
    }
    int tot = __shfl(x, 63, 64);

    offs[lane] = 0x7fffffff;
    __syncthreads();
    if (lane < nc) offs[lane + 1] = x;
    if (lane == 0) offs[0] = 0;
    __syncthreads();

    bool bad = (ovfmask != 0ull) || (tot < K) || (tot > 4096);
    if (lane == 0) badf[bl] = bad ? 1 : 0;   // 8 blocks write same value: benign
    if (bad) return;

    // gather window [w*512, w*512+512) from segments (6-step static search on offs)
    const unsigned long long* lb = loose + loose_base(l) + (size_t)b * nc * cap;
    unsigned long long v[8];
#pragma unroll
    for (int r = 0; r < 8; r++) {
        int g = (w << 9) | (r << 6) | lane;
        unsigned long long key;
        if (g >= tot) {
            key = (unsigned long long)g;   // unique pad, < any real key
        } else {
            int c = 0, oc = 0;
#pragma unroll
            for (int step = 32; step >= 1; step >>= 1) {
                int cc = c + step;
                int ov = offs[cc];         // cc <= 63
                if (ov <= g) { c = cc; oc = ov; }
            }
            key = lb[(size_t)c * cap + (g - oc)];
        }
        v[r] = key;
    }

    StageH<2>::run(v, lane);   // descending 512-elem sort, barrier-free

    unsigned long long* dst = subl + (size_t)bl * 4096 + (w << 9);
#pragma unroll
    for (int r = 0; r < 8; r++) dst[(r << 6) | lane] = v[r];
}

// ---------------- generic LDS bitonic (descending), loop-based (fallback only) ----------------
__device__ void bitonic_desc(unsigned long long* d, int n, int tid, int nt) {
    for (int k = 2; k <= n; k <<= 1) {
        for (int j = k >> 1; j > 0; j >>= 1) {
            __syncthreads();
            for (int i = tid; i < n; i += nt) {
                int ixj = i ^ j;
                if (ixj > i) {
                    unsigned long long a = d[i], bb = d[ixj];
                    bool sw = ((i & k) == 0) ? (a < bb) : (a > bb);
                    if (sw) { d[i] = bb; d[ixj] = a; }
                }
            }
        }
    }
    __syncthreads();
}

// ---------------- sortB: merge-rank 8 sorted sublists -> global sorted cand ----------------
__global__ __launch_bounds__(512) void sortB_kernel(
    const float* __restrict__ h0, const float* __restrict__ h1, const float* __restrict__ h2,
    const int* __restrict__ pbc, const unsigned long long* __restrict__ loose,
    const int* __restrict__ badf, const unsigned long long* __restrict__ subl,
    unsigned long long* __restrict__ cand)
{
    int bl = blockIdx.x;
    int part = blockIdx.y;         // 0..3, each ranks 1024 elements
    int l = bl >> 4, b = bl & 15;
    int K = (l == 2) ? 1024 : 2000;
    int tid = threadIdx.x;

    __shared__ unsigned long long A[4096];
    unsigned long long* cd = cand + (size_t)bl * 4096;

    if (!badf[bl]) {
        const unsigned long long* sl = subl + (size_t)bl * 4096;
        for (int i = tid; i < 4096; i += 512) A[i] = sl[i];
        __syncthreads();

#pragma unroll
        for (int e0 = 0; e0 < 2; e0++) {
            int wsrc = (part << 1) | e0;      // source sublist (uniform)
            unsigned long long key = A[(wsrc << 9) | tid];
            int rank = tid;                    // position within own sorted sublist
#pragma unroll
            for (int q = 0; q < 7; q++) {
                int w2 = q + (q >= wsrc ? 1 : 0);
                int lo = 0;
                for (int h = 256; h >= 1; h >>= 1) {          // rolled: small code, 7-way MLP
                    unsigned long long p = A[(w2 << 9) + lo + h - 1];
                    lo += (p > key) ? h : 0;
                }
                unsigned long long p = A[(w2 << 9) + lo];     // lo <= 511
                rank += lo + ((p > key) ? 1 : 0);
            }
            cd[rank] = key;   // keys globally unique -> rank is a permutation
        }
    } else {
        // ---- cold exact repair: full rescan + monolithic block bitonic (never for sane inputs)
        if (part != 0) return;
        __shared__ int lh[NB];
        __shared__ int st, lc2;
        for (int i = tid; i < NB; i += 512) lh[i] = 0;
        if (tid == 0) lc2 = 0;
        __syncthreads();
        int N = layer_N(l);
        const float* hp = ((l == 0) ? h0 : (l == 1) ? h1 : h2) + (size_t)b * N;
        for (int i = tid; i < N; i += 512) atomicAdd(&lh[bucket_of(hp[i])], 1);
        __syncthreads();
        if (tid == 0) {
            int acc = 0, bidx;
            for (bidx = NB - 1; bidx > 0; bidx--) {
                acc += lh[bidx];
                if (acc >= K) break;
            }
            st = bidx;
        }
        __syncthreads();
        int t = st;
        for (int i = tid; i < N; i += 512) {
            float xx = hp[i];
            if (bucket_of(xx) >= t) {
                int pos = atomicAdd(&lc2, 1);
                if (pos < 4096)
                    A[pos] = ((unsigned long long)ord_f32(xx) << 32) | (unsigned int)(~(unsigned int)i);
            }
        }
        __syncthreads();
        for (int i = min(lc2, 4096) + tid; i < 4096; i += 512) A[i] = (unsigned long long)i;
        bitonic_desc(A, 4096, tid, 512);
        for (int i = tid; i < 4096; i += 512) cd[i] = A[i];
    }
}

// ---------------- build det: validity, stable partition, write rows ----------------
__global__ __launch_bounds__(1024) void build_kernel(
    const float* __restrict__ t0, const float* __restrict__ t1, const float* __restrict__ t2,
    const float* __restrict__ r0, const float* __restrict__ r1, const float* __restrict__ r2,
    const unsigned long long* __restrict__ cand, float* __restrict__ det)
{
    int l = blockIdx.x >> 4;
    int b = blockIdx.x & 15;
    int bl = l * 16 + b;
    int HW = (l == 0) ? 16384 : (l == 1) ? 4096 : 1024;
    int W  = (l == 0) ? 128 : (l == 1) ? 64 : 32;
    int K  = (l == 2) ? 1024 : 2000;
    float scale = (l == 0) ? 8.f : (l == 1) ? 16.f : 32.f;
    const float* tlp = (l == 0) ? t0 : (l == 1) ? t1 : t2;
    const float* brp = (l == 0) ? r0 : (l == 1) ? r1 : r2;

    const unsigned long long* srt = cand + (size_t)bl * 4096;

    __shared__ int wsum[16];
    int tid = threadIdx.x;
    int lane = tid & 63, wid = tid >> 6;

    // each thread handles k = 2*tid, 2*tid+1 (consecutive -> correct scan order)
    float s_[2], bx_[2][4];
    int f_[2];
#pragma unroll
    for (int q = 0; q < 2; q++) {
        int k = 2 * tid + q;
        f_[q] = 0;
        if (k < K) {
            unsigned long long kk = srt[k];
            unsigned int idx = ~(unsigned int)kk;
            float score = unord_f32((unsigned int)(kk >> 32));
            int sp = (int)(idx % (unsigned)HW);
            float xs = (float)(sp % W), ys = (float)(sp / W);
            float tv0 = tlp[((size_t)b * 2 + 0) * HW + sp];
            float tv1 = tlp[((size_t)b * 2 + 1) * HW + sp];
            float bv0 = brp[((size_t)b * 2 + 0) * HW + sp];
            float bv1 = brp[((size_t)b * 2 + 1) * HW + sp];
            float tlx = __fsub_rn(xs, __fadd_rn(__fmul_rn(1.5f, tv0), 2.25f));
            float tly = __fsub_rn(ys, __fadd_rn(__fmul_rn(1.5f, tv1), 2.25f));
            float brx = __fadd_rn(xs, __fadd_rn(__fmul_rn(1.5f, bv0), 2.25f));
            float bry = __fadd_rn(ys, __fadd_rn(__fmul_rn(1.5f, bv1), 2.25f));
            bool invalid = (brx < tlx) || (bry < tly);
            f_[q] = invalid ? 0 : 1;
            s_[q] = invalid ? -1.0f : score;
            bx_[q][0] = __fmul_rn(tlx, scale);
            bx_[q][1] = __fmul_rn(tly, scale);
            bx_[q][2] = __fmul_rn(brx, scale);
            bx_[q][3] = __fmul_rn(bry, scale);
        }
    }
    int mysum = f_[0] + f_[1];

    // wave-level inclusive scan
    int x = mysum;
#pragma unroll
    for (int off = 1; off < 64; off <<= 1) {
        int y = __shfl_up(x, off, 64);
        if (lane >= off) x += y;
    }
    if (lane == 63) wsum[wid] = x;
    __syncthreads();
    if (wid == 0 && lane < 16) {
        int s = wsum[lane];
#pragma unroll
        for (int off = 1; off < 16; off <<= 1) {
            int y = __shfl_up(s, off, 64);
            if (lane >= off) s += y;
        }
        wsum[lane] = s;
    }
    __syncthreads();
    int wave_off = (wid > 0) ? wsum[wid - 1] : 0;
    int V = wsum[15];
    int base_excl = (x + wave_off) - mysum;

    float* dbase = det + ((size_t)b * 3000 + (size_t)l * 1000) * 7;
#pragma unroll
    for (int q = 0; q < 2; q++) {
        int k = 2 * tid + q;
        if (k < K) {
            int pos = base_excl + (q == 1 ? f_[0] : 0);
            int rank = f_[q] ? pos : V + (k - pos);
            if (rank < 1000 && rank != 6) {
                float* drow = dbase + (size_t)rank * 7;
                drow[0] = s_[q];
                drow[1] = bx_[q][0];
                drow[2] = bx_[q][1];
                drow[3] = bx_[q][2];
                drow[4] = bx_[q][3];
                drow[5] = 0.f;
                drow[6] = 0.f;
            }
        }
    }
    if (tid == 0) {
        float lv = (float)l;
        float* drow = dbase + 6 * 7;
#pragma unroll
        for (int j = 0; j < 7; j++) drow[j] = lv;
    }
}

// ---------------- final: merge-rank of 3 sorted lists (+3 clobbered singletons) ----------------
__device__ __forceinline__ bool key_gt(float sa, int ga, float sb, int gb) {
    return (sa > sb) || (sa == sb && ga < gb);
}

__global__ __launch_bounds__(1024) void final_kernel(const float* __restrict__ det,
                                                     float* __restrict__ out)
{
    int b = blockIdx.x;
    __shared__ float sc[3000];
    int tid = threadIdx.x;
    const float* dbase = det + (size_t)b * 3000 * 7;
    for (int i = tid; i < 3000; i += 1024) sc[i] = dbase[(size_t)i * 7];
    __syncthreads();

    for (int e = tid; e < 3000; e += 1024) {
        float se = sc[e];
        int ge = e;
        int rank = 0;
#pragma unroll
        for (int lp = 0; lp < 3; lp++) {
            int lo = 0, hiB = 999;
            while (lo < hiB) {
                int mid = (lo + hiB) >> 1;
                int p = mid + (mid >= 6 ? 1 : 0);
                int g = lp * 1000 + p;
                if (key_gt(sc[g], g, se, ge)) lo = mid + 1; else hiB = mid;
            }
            rank += lo;
        }
#pragma unroll
        for (int ls = 0; ls < 3; ls++) {
            int g = ls * 1000 + 6;
            if (g != e && key_gt((float)ls, g, se, ge)) rank++;
        }
        if (rank < 1000) {
            const float* src = dbase + (size_t)e * 7;
            float* dst = out + ((size_t)b * 1000 + rank) * 7;
#pragma unroll
            for (int j = 0; j < 7; j++) dst[j] = src[j];
        }
    }
}

extern "C" void kernel_launch(void* const* d_in, const int* in_sizes, int n_in,
                              void* d_out, int out_size, void* d_ws, size_t ws_size,
                              hipStream_t stream)
{
    (void)in_sizes; (void)n_in; (void)out_size; (void)ws_size;
    const float* h0 = (const float*)d_in[0];
    const float* t0 = (const float*)d_in[1];
    const float* r0 = (const float*)d_in[2];
    const float* h1 = (const float*)d_in[3];
    const float* t1 = (const float*)d_in[4];
    const float* r1 = (const float*)d_in[5];
    const float* h2 = (const float*)d_in[6];
    const float* t2 = (const float*)d_in[7];
    const float* r2 = (const float*)d_in[8];
    float* out = (float*)d_out;

    // Workspace layout (bytes):
    //   pbc  : 848*4       = 3392      @ 0
    //   badf : 48*4        = 192       @ 3392     (always written by sortA)
    //   loose: 335872*8    = 2686976   @ 3584     (8B aligned)
    //   subl : 48*4096*8   = 1572864   @ 2690560  (8B aligned)
    //   cand : 48*4096*8   = 1572864   @ 4263424
    //   det  : 16*3000*7*4 = 1344000   @ 5836288
    char* ws = (char*)d_ws;
    int* pbc  = (int*)ws;
    int* badf = (int*)(ws + 3392);
    unsigned long long* loose = (unsigned long long*)(ws + 3584);
    unsigned long long* subl  = (unsigned long long*)(ws + 2690560);
    unsigned long long* cand  = (unsigned long long*)(ws + 4263424);
    float* det = (float*)(ws + 5836288);

    collect_kernel<<<dim3(40, 16, 3), 1024, 0, stream>>>(h0, h1, h2, pbc, loose);
    sortA_kernel<<<384, 64, 0, stream>>>(pbc, loose, subl, badf);
    sortB_kernel<<<dim3(48, 4), 512, 0, stream>>>(h0, h1, h2, pbc, loose, badf, subl, cand);
    build_kernel<<<48, 1024, 0, stream>>>(t0, t1, t2, r0, r1, r2, cand, det);
    final_kernel<<<16, 1024, 0, stream>>>(det, out);
}